// Round 5
// baseline (54.432 us; speedup 1.0000x reference)
//
#include <hip/hip_runtime.h>
#include <hip/hip_bf16.h>

// Shift3x3: out[b,c,i,j] = x[b,c, i+di(c%5), j+dj(c%5)], zero at borders.
//   c%5==0: (di,dj)=(-1, 0)   c%5==1: (0,-1)   c%5==2: (0,0)
//   c%5==3: (di,dj)=( 0,+1)   c%5==4: (+1, 0)
// Shapes: B=32, C=384, H=56, W=56, float32 in/out. Pure memory-bound.
//
// 16B (one float4) per thread-iteration, fully-coalesced lane addressing.
// Horizontal shifts (mod 1/3) get the neighbor element via __shfl.
// NT stores (R4: +9%). This round: fixed-trip-count loop (16 iters exactly,
// grid 2352x256 divides n4) + unroll-4 -> 4 independent load/store chains
// in flight per thread (R4 was 1 dependent chain; HBM was only 72% busy).

#define SH_W 56
#define SH_H 56
#define SH_C 384
#define SH_W4 14            // W/4 float4 per row
#define SH_PLANE4 784       // H * W4
#define SH_PLANE 3136       // H * W

#define SH_N4     9633792   // total float4s = 65536*147
#define SH_GRID   2352      // blocks
#define SH_STRIDE 602112    // SH_GRID*256
#define SH_ITERS  16        // SH_N4 / SH_STRIDE (exact)

typedef float f32x4 __attribute__((ext_vector_type(4)));

__global__ void __launch_bounds__(256) Shift3x3_kernel(
        const float* __restrict__ x, float* __restrict__ out) {
    const int tid  = blockIdx.x * 256 + threadIdx.x;
    const int lane = threadIdx.x & 63;
#pragma unroll 4
    for (int k = 0; k < SH_ITERS; ++k) {
        int idx   = tid + k * SH_STRIDE;
        int plane = idx / SH_PLANE4;          // b*C + c
        int rem   = idx - plane * SH_PLANE4;  // float4 within plane
        int i     = rem / SH_W4;              // row
        int j     = (rem - i * SH_W4) * 4;    // col (0,4,...,52)
        int c     = plane % SH_C;
        int mod   = c % 5;
        int base  = plane * SH_PLANE + i * SH_W + j;
        const float* p = x + base;

        f32x4 v;
        if (mod == 0) {
            if (i == 0) v = (f32x4){0.f, 0.f, 0.f, 0.f};
            else        v = *reinterpret_cast<const f32x4*>(p - SH_W);
        } else if (mod == 4) {
            if (i == SH_H - 1) v = (f32x4){0.f, 0.f, 0.f, 0.f};
            else               v = *reinterpret_cast<const f32x4*>(p + SH_W);
        } else {
            f32x4 a = *reinterpret_cast<const f32x4*>(p);  // x[j..j+3]
            if (mod == 2) {
                v = a;
            } else if (mod == 1) {
                // need x[j-1] = prev float4's .w = lane-1's a.w
                float y = __shfl_up(a.w, 1);
                if (lane == 0 && j != 0) y = p[-1];
                if (j == 0) y = 0.f;
                v = (f32x4){y, a.x, a.y, a.z};
            } else {  // mod == 3
                // need x[j+4] = next float4's .x = lane+1's a.x
                float y = __shfl_down(a.x, 1);
                if (lane == 63 && j != SH_W - 4) y = p[4];
                if (j == SH_W - 4) y = 0.f;
                v = (f32x4){a.y, a.z, a.w, y};
            }
        }
        __builtin_nontemporal_store(v, reinterpret_cast<f32x4*>(out + base));
    }
}

extern "C" void kernel_launch(void* const* d_in, const int* in_sizes, int n_in,
                              void* d_out, int out_size, void* d_ws, size_t ws_size,
                              hipStream_t stream) {
    const float* x = (const float*)d_in[0];
    float* out = (float*)d_out;
    // out_size == SH_N4*4 == 38,535,168 floats; sizes are compile-time fixed.
    Shift3x3_kernel<<<SH_GRID, 256, 0, stream>>>(x, out);
}

// Round 6
// 50.466 us; speedup vs baseline: 1.0786x; 1.0786x over previous
//
#include <hip/hip_runtime.h>
#include <hip/hip_bf16.h>

// Shift3x3: out[b,c,i,j] = x[b,c, i+di(c%5), j+dj(c%5)], zero at borders.
//   c%5==0: (di,dj)=(-1, 0)   c%5==1: (0,-1)   c%5==2: (0,0)
//   c%5==3: (di,dj)=( 0,+1)   c%5==4: (+1, 0)
// Shapes: B=32, C=384, H=56, W=56, float32 in/out. Pure memory-bound.
//
// 16B (one float4) per thread-iteration, fully-coalesced lane addressing.
// Horizontal shifts (mod 1/3) via __shfl from the neighbor lane. NT stores.
// Grid: 1792 blocks = EXACTLY 7 blocks/CU (28/32 waves), and
// 1792*256*21 == n4 exactly -> no bounds check, no straggler tail
// (R5's 2352-block grid left a 304-block tail: 9.19 blocks/CU, +9% time).
// unroll 3 gives 3 independent load/store chains per thread.

#define SH_W 56
#define SH_H 56
#define SH_C 384
#define SH_W4 14            // W/4 float4 per row
#define SH_PLANE4 784       // H * W4
#define SH_PLANE 3136       // H * W

#define SH_GRID   1792      // blocks; 7 per CU exactly
#define SH_STRIDE 458752    // SH_GRID*256 threads
#define SH_ITERS  21        // 458752*21 == 9,633,792 == n4 (exact)

typedef float f32x4 __attribute__((ext_vector_type(4)));

__global__ void __launch_bounds__(256) Shift3x3_kernel(
        const float* __restrict__ x, float* __restrict__ out) {
    const int tid  = blockIdx.x * 256 + threadIdx.x;
    const int lane = threadIdx.x & 63;
#pragma unroll 3
    for (int k = 0; k < SH_ITERS; ++k) {
        int idx   = tid + k * SH_STRIDE;
        int plane = idx / SH_PLANE4;          // b*C + c
        int rem   = idx - plane * SH_PLANE4;  // float4 within plane
        int i     = rem / SH_W4;              // row
        int j     = (rem - i * SH_W4) * 4;    // col (0,4,...,52)
        int c     = plane % SH_C;
        int mod   = c % 5;
        int base  = plane * SH_PLANE + i * SH_W + j;
        const float* p = x + base;

        f32x4 v;
        if (mod == 0) {
            if (i == 0) v = (f32x4){0.f, 0.f, 0.f, 0.f};
            else        v = *reinterpret_cast<const f32x4*>(p - SH_W);
        } else if (mod == 4) {
            if (i == SH_H - 1) v = (f32x4){0.f, 0.f, 0.f, 0.f};
            else               v = *reinterpret_cast<const f32x4*>(p + SH_W);
        } else {
            f32x4 a = *reinterpret_cast<const f32x4*>(p);  // x[j..j+3]
            if (mod == 2) {
                v = a;
            } else if (mod == 1) {
                // need x[j-1] = prev float4's .w = lane-1's a.w
                float y = __shfl_up(a.w, 1);
                if (lane == 0 && j != 0) y = p[-1];
                if (j == 0) y = 0.f;
                v = (f32x4){y, a.x, a.y, a.z};
            } else {  // mod == 3
                // need x[j+4] = next float4's .x = lane+1's a.x
                float y = __shfl_down(a.x, 1);
                if (lane == 63 && j != SH_W - 4) y = p[4];
                if (j == SH_W - 4) y = 0.f;
                v = (f32x4){a.y, a.z, a.w, y};
            }
        }
        __builtin_nontemporal_store(v, reinterpret_cast<f32x4*>(out + base));
    }
}

extern "C" void kernel_launch(void* const* d_in, const int* in_sizes, int n_in,
                              void* d_out, int out_size, void* d_ws, size_t ws_size,
                              hipStream_t stream) {
    const float* x = (const float*)d_in[0];
    float* out = (float*)d_out;
    // out_size == 38,535,168 floats (compile-time fixed shapes).
    Shift3x3_kernel<<<SH_GRID, 256, 0, stream>>>(x, out);
}

// Round 7
// 50.261 us; speedup vs baseline: 1.0830x; 1.0041x over previous
//
#include <hip/hip_runtime.h>
#include <hip/hip_bf16.h>

// Shift3x3: out[b,c,i,j] = x[b,c, i+di(c%5), j+dj(c%5)], zero at borders.
//   c%5==0: (di,dj)=(-1, 0)   c%5==1: (0,-1)   c%5==2: (0,0)
//   c%5==3: (di,dj)=( 0,+1)   c%5==4: (+1, 0)
// Shapes: B=32, C=384, H=56, W=56, float32 in/out. Pure memory-bound.
//
// FINAL (best-measured config, = Round-4: 49.9 us, 6.17 TB/s logical = 98%
// of the 6.29 TB/s measured copy ceiling):
//  - 16B (one float4) per thread-iteration, per-instruction lane addresses
//    fully contiguous (1KB/wave-instruction). 32B/thread regressed (R2):
//    per-instruction coalescing beats per-thread bytes.
//  - Horizontal shifts (mod 1/3) reuse the aligned float4; neighbor element
//    via __shfl from lane +/-1; wave-edge lanes take one exec-masked scalar.
//  - NT stores (+9%, R4): output is write-once, never re-read.
//  - grid 2048 = exactly 8 blocks/CU (32 waves, full occupancy, no tail
//    imbalance; 2352 blocks regressed +9% in R5 from a 304-block tail).
//  - ILP experiments (R5 unroll4-fixed-trip, R6 unroll3-balanced) were
//    neutral-to-negative: the kernel is at the mixed read+write BW ceiling.

#define SH_W 56
#define SH_H 56
#define SH_C 384
#define SH_W4 14            // W/4 float4 per row
#define SH_PLANE4 784       // H * W4
#define SH_PLANE 3136       // H * W

typedef float f32x4 __attribute__((ext_vector_type(4)));

__global__ void __launch_bounds__(256) Shift3x3_kernel(
        const float* __restrict__ x, float* __restrict__ out, int n4) {
    int idx = blockIdx.x * blockDim.x + threadIdx.x;
    const int stride = gridDim.x * blockDim.x;
    const int lane = threadIdx.x & 63;
    for (; idx < n4; idx += stride) {
        int plane = idx / SH_PLANE4;          // b*C + c
        int rem   = idx - plane * SH_PLANE4;  // float4 within plane
        int i     = rem / SH_W4;              // row
        int j     = (rem - i * SH_W4) * 4;    // col (0,4,...,52)
        int c     = plane % SH_C;
        int mod   = c % 5;
        int base  = plane * SH_PLANE + i * SH_W + j;
        const float* p = x + base;

        f32x4 v;
        if (mod == 0) {
            if (i == 0) v = (f32x4){0.f, 0.f, 0.f, 0.f};
            else        v = *reinterpret_cast<const f32x4*>(p - SH_W);
        } else if (mod == 4) {
            if (i == SH_H - 1) v = (f32x4){0.f, 0.f, 0.f, 0.f};
            else               v = *reinterpret_cast<const f32x4*>(p + SH_W);
        } else {
            f32x4 a = *reinterpret_cast<const f32x4*>(p);  // x[j..j+3]
            if (mod == 2) {
                v = a;
            } else if (mod == 1) {
                // need x[j-1] = prev float4's .w = lane-1's a.w
                float y = __shfl_up(a.w, 1);
                if (lane == 0 && j != 0) y = p[-1];
                if (j == 0) y = 0.f;
                v = (f32x4){y, a.x, a.y, a.z};
            } else {  // mod == 3
                // need x[j+4] = next float4's .x = lane+1's a.x
                float y = __shfl_down(a.x, 1);
                if (lane == 63 && j != SH_W - 4) y = p[4];
                if (j == SH_W - 4) y = 0.f;
                v = (f32x4){a.y, a.z, a.w, y};
            }
        }
        __builtin_nontemporal_store(v, reinterpret_cast<f32x4*>(out + base));
    }
}

extern "C" void kernel_launch(void* const* d_in, const int* in_sizes, int n_in,
                              void* d_out, int out_size, void* d_ws, size_t ws_size,
                              hipStream_t stream) {
    const float* x = (const float*)d_in[0];
    float* out = (float*)d_out;
    int n4 = out_size / 4;  // 9,633,792 float4 stores
    int block = 256;
    int grid = (n4 + block - 1) / block;
    if (grid > 2048) grid = 2048;   // exactly 8 blocks/CU on 256 CUs
    Shift3x3_kernel<<<grid, block, 0, stream>>>(x, out, n4);
}